// Round 8
// baseline (752.501 us; speedup 1.0000x reference)
//
#include <hip/hip_runtime.h>

#define NPTS 8192
#define NCH 8
#define STRIDE 6144
#define TOTAL 51200
#define FADE 1228
#define NBLK 256u

// ---------------------------------------------------------------------------
// Agent-scope relaxed accessors (serviced at device coherence point).
__device__ __forceinline__ float aload(const float* p) {
    return __hip_atomic_load(p, __ATOMIC_RELAXED, __HIP_MEMORY_SCOPE_AGENT);
}
__device__ __forceinline__ void astore(float* p, float v) {
    __hip_atomic_store(p, v, __ATOMIC_RELAXED, __HIP_MEMORY_SCOPE_AGENT);
}
__device__ __forceinline__ int aloadi(const int* p) {
    return __hip_atomic_load(p, __ATOMIC_RELAXED, __HIP_MEMORY_SCOPE_AGENT);
}

// Grid barrier: per-wave vmem drain + block barrier + one relaxed agent-scope
// arrive; spin with s_sleep backoff to avoid hammering the coherence point.
__device__ __forceinline__ void gsync(unsigned* bar, int slot) {
    __atomic_signal_fence(__ATOMIC_SEQ_CST);
    __builtin_amdgcn_s_waitcnt(0);
    __syncthreads();
    if (threadIdx.x == 0) {
        __hip_atomic_fetch_add(&bar[slot], 1u, __ATOMIC_RELAXED, __HIP_MEMORY_SCOPE_AGENT);
        while (__hip_atomic_load(&bar[slot], __ATOMIC_RELAXED, __HIP_MEMORY_SCOPE_AGENT) < NBLK)
            __builtin_amdgcn_s_sleep(2);
    }
    __syncthreads();
    __atomic_signal_fence(__ATOMIC_SEQ_CST);
}

// LDS layout (bytes), union of phases:
//  phase A: SH4 [0,33280) staged cands | PART [33280,58240) partial (d,k)
//  phase C: W2 [0,20480) | B2 [20480,20608) | F [20608,21136)
//           H1 [21136,26384) | H2 [26384,31120)
//  persistent within pair: QL [58240,59008) | FUSEDL [59008,59584) | MIL [59584,59776)
#define OFF_PART   33280
#define OFF_QL     58240
#define OFF_FUSEDL 59008
#define OFF_MIL    59584
#define OFF_B2     20480
#define OFF_F      20608
#define OFF_H1     21136
#define OFF_H2     26384

__global__ __launch_bounds__(512, 2) void k_fusion(
        const float* __restrict__ chunks,
        const float* __restrict__ bw1, const float* __restrict__ bb1,
        const float* __restrict__ bw2, const float* __restrict__ bb2,
        const float* __restrict__ bw3, const float* __restrict__ bb3,
        const float* __restrict__ pw1, const float* __restrict__ pb1,
        const float* __restrict__ pw2, const float* __restrict__ pb2,
        const float* __restrict__ pw3, const float* __restrict__ pb3,
        unsigned* bar, int* __restrict__ jmax_all,
        float* __restrict__ smfull, float* __restrict__ out) {
#pragma clang fp contract(off)
    __shared__ __align__(16) char smem[59776];
    float4* SH4 = (float4*)smem;
    unsigned long long* PART = (unsigned long long*)(smem + OFF_PART);
    float* QL     = (float*)(smem + OFF_QL);       // [48][4]: x,y,z,pp
    float* FUSEDL = (float*)(smem + OFF_FUSEDL);   // [3][48]
    int*   MIL    = (int*)(smem + OFF_MIL);        // [48]
    float* W2 = (float*)smem;
    float* B2 = (float*)(smem + OFF_B2);
    float* F  = (float*)(smem + OFF_F);
    float* H1 = (float*)(smem + OFF_H1);
    float* H2 = (float*)(smem + OFF_H2);

    int tid = threadIdx.x;
    int bid = blockIdx.x;
    int BASE = bid * 32;
    int qg = tid & 7;         // 8 query groups x 6 queries
    int sr = tid >> 3;        // 64 cand-range ids (128 cands each across 4 stages)

    for (int pair = 1; pair < NCH; ++pair) {
        const float* Cc = chunks + pair * NPTS * 3;          // candidates (raw chunk)
        const float* chPrev = chunks + (pair - 1) * NPTS * 3;
        const float* smPrev = smfull + (pair - 2) * NPTS * 3; // valid for pair>=2
        const int* jmaxPrev = jmax_all + (pair - 2) * NPTS;
        float* smCur = smfull + (pair - 1) * NPTS * 3;
        int* jmaxCur = jmax_all + (pair - 1) * NPTS;

        // ---- gather widened queries [BASE-8, BASE+40) into QL ----
        if (tid < 48) {
            int j = BASE - 8 + tid;
            if (j < 0) j = 0; else if (j >= NPTS) j = NPTS - 1;  // edge lanes: unused results
            float x, y, z;
            if (pair == 1) {
                x = chunks[j * 3 + 0]; y = chunks[j * 3 + 1]; z = chunks[j * 3 + 2];
            } else {
                int jm = aloadi(&jmaxPrev[j]);
                if (jm > 0) {
                    const float* r = smPrev + (jm - 1) * 3;
                    x = aload(r); y = aload(r + 1); z = aload(r + 2);
                } else {
                    x = chPrev[j * 3 + 0]; y = chPrev[j * 3 + 1]; z = chPrev[j * 3 + 2];
                }
            }
            QL[tid * 4 + 0] = x; QL[tid * 4 + 1] = y; QL[tid * 4 + 2] = z;
            QL[tid * 4 + 3] = (x * x + y * y) + z * z;
        }
        __syncthreads();

        // ---- phase A: argmin (brute force, block-complete over widened queries) ----
        float q0[6], q1[6], q2[6], pp[6], best[6];
        int bk[6];
#pragma unroll
        for (int jq = 0; jq < 6; ++jq) {
            int lq = qg * 6 + jq;
            q0[jq] = QL[lq * 4 + 0]; q1[jq] = QL[lq * 4 + 1];
            q2[jq] = QL[lq * 4 + 2]; pp[jq] = QL[lq * 4 + 3];
            best[jq] = 3.4e38f; bk[jq] = 0;
        }
        int sbase = (sr >> 1) * 65 + (sr & 1) * 32;
        for (int st = 0; st < 4; ++st) {
            {   // stage 2048 cands: thread loads 4 cands (3 float4)
                const float4* src = (const float4*)(Cc + (st * 2048 + tid * 4) * 3);
                float4 v0 = src[0], v1 = src[1], v2 = src[2];
                int wbase = (tid >> 4) * 65 + (tid & 15) * 4;
                float xs[4] = {v0.x, v0.w, v1.z, v2.y};
                float ys[4] = {v0.y, v1.x, v1.w, v2.z};
                float zs[4] = {v0.z, v1.y, v2.x, v2.w};
#pragma unroll
                for (int u = 0; u < 4; ++u) {
                    float x = xs[u], y = ys[u], z = zs[u];
                    float cc = (x * x + y * y) + z * z;
                    SH4[wbase + u] = make_float4(x, y, z, cc);
                }
            }
            __syncthreads();
            int kab = st * 2048 + sr * 32;
#pragma unroll 2
            for (int i = 0; i < 32; ++i) {
                float4 f = SH4[sbase + i];
                int kk = kab + i;
#pragma unroll
                for (int jq = 0; jq < 6; ++jq) {
                    float g = __builtin_fmaf(q2[jq], f.z,
                              __builtin_fmaf(q1[jq], f.y, q0[jq] * f.x));
                    float sadd = pp[jq] + f.w;
                    float d = __builtin_fmaf(-2.0f, g, sadd);
                    if (d < best[jq]) { best[jq] = d; bk[jq] = kk; }   // strict <
                }
            }
            __syncthreads();
        }
        // partials: order-preserving (d,k) pack; u64 min == ascending strict-< winner
#pragma unroll
        for (int jq = 0; jq < 6; ++jq) {
            unsigned ud = __float_as_uint(best[jq]);
            if (ud == 0x80000000u) ud = 0u;
            ud = (ud & 0x80000000u) ? ~ud : (ud | 0x80000000u);
            PART[(qg * 6 + jq) * 65 + sr] =
                ((unsigned long long)ud << 32) | (unsigned long long)(unsigned)bk[jq];
        }
        __syncthreads();

        // ---- merge + MLP + fused (threads 0..47) + jmax for own 32 queries ----
        if (tid < 48) {
            unsigned long long bb = PART[tid * 65];
#pragma unroll
            for (int s = 1; s < 64; ++s) {
                unsigned long long v = PART[tid * 65 + s];
                if (v < bb) bb = v;
            }
            int m = (int)(unsigned)(bb & 0xFFFFFFFFull);
            MIL[tid] = m;
            float x6[6];
            x6[0] = QL[tid * 4 + 0]; x6[1] = QL[tid * 4 + 1]; x6[2] = QL[tid * 4 + 2];
            x6[3] = Cc[m * 3 + 0]; x6[4] = Cc[m * 3 + 1]; x6[5] = Cc[m * 3 + 2];
            float h1[32];
#pragma unroll
            for (int o = 0; o < 32; ++o) {
                float acc = 0.0f;
#pragma unroll
                for (int ci = 0; ci < 6; ++ci) acc = __builtin_fmaf(x6[ci], pw1[o * 6 + ci], acc);
                h1[o] = fmaxf(acc + pb1[o], 0.0f);
            }
            float h2[16];
#pragma unroll
            for (int o = 0; o < 16; ++o) {
                float acc = 0.0f;
#pragma unroll
                for (int ci = 0; ci < 32; ++ci) acc = __builtin_fmaf(h1[ci], pw2[o * 32 + ci], acc);
                h2[o] = fmaxf(acc + pb2[o], 0.0f);
            }
            float acc = 0.0f;
#pragma unroll
            for (int ci = 0; ci < 16; ++ci) acc = __builtin_fmaf(h2[ci], pw3[ci], acc);
            float z = acc + pb3[0];
            float w = 1.0f / (1.0f + expf(-z));
            float omw = 1.0f - w;
#pragma unroll
            for (int e = 0; e < 3; ++e) {
                float t1 = w * x6[e];
                float t2 = omw * x6[3 + e];
                FUSEDL[e * 48 + tid] = t1 + t2;
            }
            // own queries: lq in [8,40) <=> j in [BASE, BASE+32); max-j-wins dedupe
            if (tid >= 8 && tid < 40) {
                bool issue = true;
                for (int s = 1; s < 32; ++s) {
                    int om = __shfl_down(m, s);
                    if (tid + s < 40 && om == m) issue = false;
                }
                if (issue) atomicMax(&jmaxCur[m], BASE + tid - 8 + 1);   // store j+1
            }
        }
        __syncthreads();

        // ---- phase C: smoother (fused from LDS) -> smCur (own 32 rows) ----
        for (int li = tid; li < 132; li += 512) {
            int c = li / 44, i = li % 44;
            int t = BASE - 6 + i;
            F[c * 44 + i] = (t >= 0 && t < NPTS) ? FUSEDL[c * 48 + (i + 2)] : 0.0f;
        }
        for (int o = tid; o < 5120; o += 512) {
            int co = o & 31, r = o >> 5;          // r = ci*5 + k
            int ci = r / 5, k = r - ci * 5;
            W2[o] = bw2[(co * 32 + ci) * 5 + k];
        }
        if (tid < 32) B2[tid] = bb2[tid];
        __syncthreads();

        {   // conv1 -> H1 on [BASE-4, BASE+36)
            int co = tid >> 4, pg = tid & 15;
            float wr[15];
#pragma unroll
            for (int q = 0; q < 15; ++q) wr[q] = bw1[co * 15 + q];
            float bias = bb1[co];
            for (int i = pg; i < 40; i += 16) {
                int t = BASE - 4 + i;
                float acc = 0.0f;
#pragma unroll
                for (int k = 0; k < 5; ++k)
#pragma unroll
                    for (int ci = 0; ci < 3; ++ci)
                        acc = __builtin_fmaf(F[ci * 44 + i + k], wr[ci * 5 + k], acc);
                H1[co * 41 + i] = (t >= 0 && t < NPTS) ? fmaxf(acc + bias, 0.0f) : 0.0f;
            }
        }
        __syncthreads();

        {   // conv2 -> H2 on [BASE-2, BASE+34): 8 co-quads x 36 positions
            int cq = tid & 7, pos = tid >> 3;
            if (pos < 36) {
                int co0 = cq * 4;
                float a0 = 0.f, a1 = 0.f, a2 = 0.f, a3 = 0.f;
                for (int k = 0; k < 5; ++k) {
#pragma unroll
                    for (int ci = 0; ci < 32; ++ci) {
                        float in0 = H1[ci * 41 + pos + k];
                        const float4 wv = *(const float4*)&W2[(ci * 5 + k) * 32 + co0];
                        a0 = __builtin_fmaf(in0, wv.x, a0);
                        a1 = __builtin_fmaf(in0, wv.y, a1);
                        a2 = __builtin_fmaf(in0, wv.z, a2);
                        a3 = __builtin_fmaf(in0, wv.w, a3);
                    }
                }
                int t0 = BASE - 2 + pos;
                bool ok = (t0 >= 0 && t0 < NPTS);
                H2[(co0 + 0) * 37 + pos] = ok ? fmaxf(a0 + B2[co0 + 0], 0.0f) : 0.0f;
                H2[(co0 + 1) * 37 + pos] = ok ? fmaxf(a1 + B2[co0 + 1], 0.0f) : 0.0f;
                H2[(co0 + 2) * 37 + pos] = ok ? fmaxf(a2 + B2[co0 + 2], 0.0f) : 0.0f;
                H2[(co0 + 3) * 37 + pos] = ok ? fmaxf(a3 + B2[co0 + 3], 0.0f) : 0.0f;
            }
        }
        __syncthreads();

        if (tid < 96) {   // conv3 -> smCur rows [BASE, BASE+32)
            int co = tid >> 5, p = tid & 31;
            float wr[160];
            const float4* w3v = (const float4*)(bw3 + co * 160);
#pragma unroll
            for (int q = 0; q < 40; ++q) {
                float4 v = w3v[q];
                wr[q * 4 + 0] = v.x; wr[q * 4 + 1] = v.y;
                wr[q * 4 + 2] = v.z; wr[q * 4 + 3] = v.w;
            }
            float acc = 0.0f;
#pragma unroll
            for (int k = 0; k < 5; ++k)
#pragma unroll
                for (int ci = 0; ci < 32; ++ci)
                    acc = __builtin_fmaf(H2[ci * 37 + p + k], wr[ci * 5 + k], acc);
            astore(&smCur[(BASE + p) * 3 + co], acc + bb3[co]);
        }

        gsync(bar, pair - 1);   // one barrier per pair
    }

    // ---------------- merge (smoothed[p] = smfull[p] for p<7; p=7 gathered) ----------------
    {
        int pos = bid * 512 + tid;
        if (pos < TOTAL) {
            int imax = pos / STRIDE; if (imax > NCH - 1) imax = NCH - 1;
            int imin = (pos >= NPTS) ? ((pos - NPTS) / STRIDE + 1) : 0;
            float a0 = 0.0f, a1 = 0.0f, a2 = 0.0f, wsum = 0.0f;
            const float kstep = 0.9f / 1227.0f;
            const int* jmax7 = jmax_all + 6 * NPTS;
            const float* sm7 = smfull + 6 * NPTS * 3;
            for (int i = imin; i <= imax; ++i) {
                int t = pos - i * STRIDE;
                float cw;
                if (t < FADE)                cw = 0.1f + (float)t * kstep;
                else if (t >= NPTS - FADE)   cw = 1.0f - (float)(t - (NPTS - FADE)) * kstep;
                else                         cw = 1.0f;
                float vx, vy, vz;
                if (i < 7) {
                    const float* v = smfull + (i * NPTS + t) * 3;
                    vx = aload(v); vy = aload(v + 1); vz = aload(v + 2);
                } else {
                    int jm = aloadi(&jmax7[t]);
                    if (jm > 0) {
                        const float* v = sm7 + (jm - 1) * 3;
                        vx = aload(v); vy = aload(v + 1); vz = aload(v + 2);
                    } else {
                        const float* v = chunks + (7 * NPTS + t) * 3;
                        vx = v[0]; vy = v[1]; vz = v[2];
                    }
                }
                a0 += cw * vx;
                a1 += cw * vy;
                a2 += cw * vz;
                wsum += cw;
            }
            float wm = fmaxf(wsum, 1e-8f);
            out[pos * 3 + 0] = a0 / wm;
            out[pos * 3 + 1] = a1 / wm;
            out[pos * 3 + 2] = a2 / wm;
        }
    }
}

// ---------------------------------------------------------------------------
extern "C" void kernel_launch(void* const* d_in, const int* in_sizes, int n_in,
                              void* d_out, int out_size, void* d_ws, size_t ws_size,
                              hipStream_t stream) {
    const float* chunks = (const float*)d_in[0];
    const float* bs_w1 = (const float*)d_in[1];
    const float* bs_b1 = (const float*)d_in[2];
    const float* bs_w2 = (const float*)d_in[3];
    const float* bs_b2 = (const float*)d_in[4];
    const float* bs_w3 = (const float*)d_in[5];
    const float* bs_b3 = (const float*)d_in[6];
    const float* wp_w1 = (const float*)d_in[7];
    const float* wp_b1 = (const float*)d_in[8];
    const float* wp_w2 = (const float*)d_in[9];
    const float* wp_b2 = (const float*)d_in[10];
    const float* wp_w3 = (const float*)d_in[11];
    const float* wp_b3 = (const float*)d_in[12];

    unsigned* bar   = (unsigned*)d_ws;                         // 128 B (7 slots used)
    int* jmax_all   = (int*)((char*)d_ws + 128);               // 7*8192 i32 = 229376 B
    float* smfull   = (float*)((char*)d_ws + 128 + 229376);    // 7*8192*3 f32
    float* out      = (float*)d_out;

    // zero barrier slots + jmax (j+1 encoding => 0 means "no match")
    hipMemsetAsync(d_ws, 0, 128 + 229376, stream);

    k_fusion<<<256, 512, 0, stream>>>(chunks,
        bs_w1, bs_b1, bs_w2, bs_b2, bs_w3, bs_b3,
        wp_w1, wp_b1, wp_w2, wp_b2, wp_w3, wp_b3,
        bar, jmax_all, smfull, out);
}

// Round 9
// 703.546 us; speedup vs baseline: 1.0696x; 1.0696x over previous
//
#include <hip/hip_runtime.h>

#define NPTS 8192
#define NCH 8
#define STRIDE 6144
#define TOTAL 51200
#define FADE 1228
#define NBLK 256u

// ---------------------------------------------------------------------------
// Agent-scope relaxed accessors (serviced at device coherence point).
__device__ __forceinline__ float aload(const float* p) {
    return __hip_atomic_load(p, __ATOMIC_RELAXED, __HIP_MEMORY_SCOPE_AGENT);
}
__device__ __forceinline__ void astore(float* p, float v) {
    __hip_atomic_store(p, v, __ATOMIC_RELAXED, __HIP_MEMORY_SCOPE_AGENT);
}
__device__ __forceinline__ int aloadi(const int* p) {
    return __hip_atomic_load(p, __ATOMIC_RELAXED, __HIP_MEMORY_SCOPE_AGENT);
}

// Grid barrier: per-wave vmem drain + block barrier + one relaxed agent-scope
// arrive; spin with s_sleep backoff.
__device__ __forceinline__ void gsync(unsigned* bar, int slot) {
    __atomic_signal_fence(__ATOMIC_SEQ_CST);
    __builtin_amdgcn_s_waitcnt(0);
    __syncthreads();
    if (threadIdx.x == 0) {
        __hip_atomic_fetch_add(&bar[slot], 1u, __ATOMIC_RELAXED, __HIP_MEMORY_SCOPE_AGENT);
        while (__hip_atomic_load(&bar[slot], __ATOMIC_RELAXED, __HIP_MEMORY_SCOPE_AGENT) < NBLK)
            __builtin_amdgcn_s_sleep(2);
    }
    __syncthreads();
    __atomic_signal_fence(__ATOMIC_SEQ_CST);
}

// LDS layout (bytes), union of phases:
//  phase A: SH4 [0,33280) staged cands | PART [33280,58240) partial (d,k)
//  phase C: W2 [0,20480) | B2 [20480,20608) | F [20608,21136)
//           H1 [21136,26384) | H2 [26384,31120) | W3 [31120,33040)
//  persistent within pair: QL [58240,59008) | FUSEDL [59008,59584) | MIL [59584,59776)
#define OFF_PART   33280
#define OFF_QL     58240
#define OFF_FUSEDL 59008
#define OFF_MIL    59584
#define OFF_B2     20480
#define OFF_F      20608
#define OFF_H1     21136
#define OFF_H2     26384
#define OFF_W3     31120

__global__ __launch_bounds__(512, 2) void k_fusion(
        const float* __restrict__ chunks,
        const float* __restrict__ bw1, const float* __restrict__ bb1,
        const float* __restrict__ bw2, const float* __restrict__ bb2,
        const float* __restrict__ bw3, const float* __restrict__ bb3,
        const float* __restrict__ pw1, const float* __restrict__ pb1,
        const float* __restrict__ pw2, const float* __restrict__ pb2,
        const float* __restrict__ pw3, const float* __restrict__ pb3,
        unsigned* bar, int* __restrict__ jmax_all,
        float* __restrict__ smfull, float* __restrict__ out) {
#pragma clang fp contract(off)
    __shared__ __align__(16) char smem[59776];
    float4* SH4 = (float4*)smem;
    unsigned long long* PART = (unsigned long long*)(smem + OFF_PART);
    float* QL     = (float*)(smem + OFF_QL);       // [48][4]: x,y,z,pp
    float* FUSEDL = (float*)(smem + OFF_FUSEDL);   // [3][48]
    int*   MIL    = (int*)(smem + OFF_MIL);        // [48]
    float* W2  = (float*)smem;
    float* B2  = (float*)(smem + OFF_B2);
    float* F   = (float*)(smem + OFF_F);
    float* H1  = (float*)(smem + OFF_H1);
    float* H2  = (float*)(smem + OFF_H2);
    float* W3L = (float*)(smem + OFF_W3);          // 480 floats

    int tid = threadIdx.x;
    int bid = blockIdx.x;
    int BASE = bid * 32;
    int qg = tid & 7;         // 8 query groups x 6 queries
    int sr = tid >> 3;        // 64 cand-range ids

    for (int pair = 1; pair < NCH; ++pair) {
        const float* Cc = chunks + pair * NPTS * 3;
        const float* chPrev = chunks + (pair - 1) * NPTS * 3;
        const float* smPrev = smfull + (pair - 2) * NPTS * 3;  // valid for pair>=2
        const int* jmaxPrev = jmax_all + (pair - 2) * NPTS;
        float* smCur = smfull + (pair - 1) * NPTS * 3;
        int* jmaxCur = jmax_all + (pair - 1) * NPTS;

        // ---- gather widened queries [BASE-8, BASE+40) into QL ----
        if (tid < 48) {
            int j = BASE - 8 + tid;
            if (j < 0) j = 0; else if (j >= NPTS) j = NPTS - 1;  // edge lanes unused
            float x, y, z;
            if (pair == 1) {
                x = chunks[j * 3 + 0]; y = chunks[j * 3 + 1]; z = chunks[j * 3 + 2];
            } else {
                int jm = aloadi(&jmaxPrev[j]);
                if (jm > 0) {
                    const float* r = smPrev + (jm - 1) * 3;
                    x = aload(r); y = aload(r + 1); z = aload(r + 2);
                } else {
                    x = chPrev[j * 3 + 0]; y = chPrev[j * 3 + 1]; z = chPrev[j * 3 + 2];
                }
            }
            QL[tid * 4 + 0] = x; QL[tid * 4 + 1] = y; QL[tid * 4 + 2] = z;
            QL[tid * 4 + 3] = (x * x + y * y) + z * z;
        }
        __syncthreads();

        // ---- phase A: argmin (brute force, block-complete over widened queries) ----
        float q0[6], q1[6], q2[6], pp[6], best[6];
        int bk[6];
#pragma unroll
        for (int jq = 0; jq < 6; ++jq) {
            int lq = qg * 6 + jq;
            q0[jq] = QL[lq * 4 + 0]; q1[jq] = QL[lq * 4 + 1];
            q2[jq] = QL[lq * 4 + 2]; pp[jq] = QL[lq * 4 + 3];
            best[jq] = 3.4e38f; bk[jq] = 0;
        }
        int sbase = (sr >> 1) * 65 + (sr & 1) * 32;
        for (int st = 0; st < 4; ++st) {
            {   // stage 2048 cands: thread loads 4 cands (3 float4)
                const float4* src = (const float4*)(Cc + (st * 2048 + tid * 4) * 3);
                float4 v0 = src[0], v1 = src[1], v2 = src[2];
                int wbase = (tid >> 4) * 65 + (tid & 15) * 4;
                float xs[4] = {v0.x, v0.w, v1.z, v2.y};
                float ys[4] = {v0.y, v1.x, v1.w, v2.z};
                float zs[4] = {v0.z, v1.y, v2.x, v2.w};
#pragma unroll
                for (int u = 0; u < 4; ++u) {
                    float x = xs[u], y = ys[u], z = zs[u];
                    float cc = (x * x + y * y) + z * z;
                    SH4[wbase + u] = make_float4(x, y, z, cc);
                }
            }
            __syncthreads();
            int kab = st * 2048 + sr * 32;
#pragma unroll 2
            for (int i = 0; i < 32; ++i) {
                float4 f = SH4[sbase + i];
                int kk = kab + i;
#pragma unroll
                for (int jq = 0; jq < 6; ++jq) {
                    float g = __builtin_fmaf(q2[jq], f.z,
                              __builtin_fmaf(q1[jq], f.y, q0[jq] * f.x));
                    float sadd = pp[jq] + f.w;
                    float d = __builtin_fmaf(-2.0f, g, sadd);
                    if (d < best[jq]) { best[jq] = d; bk[jq] = kk; }   // strict <
                }
            }
            __syncthreads();
        }
        // partials: order-preserving (d,k) pack; u64 min == ascending strict-< winner
#pragma unroll
        for (int jq = 0; jq < 6; ++jq) {
            unsigned ud = __float_as_uint(best[jq]);
            if (ud == 0x80000000u) ud = 0u;
            ud = (ud & 0x80000000u) ? ~ud : (ud | 0x80000000u);
            PART[(qg * 6 + jq) * 65 + sr] =
                ((unsigned long long)ud << 32) | (unsigned long long)(unsigned)bk[jq];
        }
        __syncthreads();

        // ---- merge + MLP + fused (threads 0..47) + jmax for own 32 queries ----
        if (tid < 48) {
            unsigned long long bb = PART[tid * 65];
#pragma unroll
            for (int s = 1; s < 64; ++s) {
                unsigned long long v = PART[tid * 65 + s];
                if (v < bb) bb = v;
            }
            int m = (int)(unsigned)(bb & 0xFFFFFFFFull);
            MIL[tid] = m;
            float x6[6];
            x6[0] = QL[tid * 4 + 0]; x6[1] = QL[tid * 4 + 1]; x6[2] = QL[tid * 4 + 2];
            x6[3] = Cc[m * 3 + 0]; x6[4] = Cc[m * 3 + 1]; x6[5] = Cc[m * 3 + 2];
            float h1[32];
#pragma unroll
            for (int o = 0; o < 32; ++o) {
                float acc = 0.0f;
#pragma unroll
                for (int ci = 0; ci < 6; ++ci) acc = __builtin_fmaf(x6[ci], pw1[o * 6 + ci], acc);
                h1[o] = fmaxf(acc + pb1[o], 0.0f);
            }
            float h2[16];
#pragma unroll
            for (int o = 0; o < 16; ++o) {
                float acc = 0.0f;
#pragma unroll
                for (int ci = 0; ci < 32; ++ci) acc = __builtin_fmaf(h1[ci], pw2[o * 32 + ci], acc);
                h2[o] = fmaxf(acc + pb2[o], 0.0f);
            }
            float acc = 0.0f;
#pragma unroll
            for (int ci = 0; ci < 16; ++ci) acc = __builtin_fmaf(h2[ci], pw3[ci], acc);
            float z = acc + pb3[0];
            float w = 1.0f / (1.0f + expf(-z));
            float omw = 1.0f - w;
#pragma unroll
            for (int e = 0; e < 3; ++e) {
                float t1 = w * x6[e];
                float t2 = omw * x6[3 + e];
                FUSEDL[e * 48 + tid] = t1 + t2;
            }
            // own queries: lq in [8,40) <=> j in [BASE, BASE+32); max-j-wins dedupe
            if (tid >= 8 && tid < 40) {
                bool issue = true;
                for (int s = 1; s < 32; ++s) {
                    int om = __shfl_down(m, s);
                    if (tid + s < 40 && om == m) issue = false;
                }
                if (issue) atomicMax(&jmaxCur[m], BASE + tid - 8 + 1);   // store j+1
            }
        }
        __syncthreads();

        // ---- phase C: smoother (fused from LDS) -> smCur (own 32 rows) ----
        for (int li = tid; li < 132; li += 512) {
            int c = li / 44, i = li % 44;
            int t = BASE - 6 + i;
            F[c * 44 + i] = (t >= 0 && t < NPTS) ? FUSEDL[c * 48 + (i + 2)] : 0.0f;
        }
        for (int o = tid; o < 5120; o += 512) {
            int co = o & 31, r = o >> 5;          // r = ci*5 + k
            int ci = r / 5, k = r - ci * 5;
            W2[o] = bw2[(co * 32 + ci) * 5 + k];
        }
        if (tid < 480) W3L[tid] = bw3[tid];       // [co*160 + ci*5 + k], native layout
        if (tid < 32) B2[tid] = bb2[tid];
        __syncthreads();

        {   // conv1 -> H1 on [BASE-4, BASE+36)
            int co = tid >> 4, pg = tid & 15;
            float wr[15];
#pragma unroll
            for (int q = 0; q < 15; ++q) wr[q] = bw1[co * 15 + q];
            float bias = bb1[co];
            for (int i = pg; i < 40; i += 16) {
                int t = BASE - 4 + i;
                float acc = 0.0f;
#pragma unroll
                for (int k = 0; k < 5; ++k)
#pragma unroll
                    for (int ci = 0; ci < 3; ++ci)
                        acc = __builtin_fmaf(F[ci * 44 + i + k], wr[ci * 5 + k], acc);
                H1[co * 41 + i] = (t >= 0 && t < NPTS) ? fmaxf(acc + bias, 0.0f) : 0.0f;
            }
        }
        __syncthreads();

        {   // conv2 -> H2 on [BASE-2, BASE+34): 8 co-quads x 36 positions
            int cq = tid & 7, pos = tid >> 3;
            if (pos < 36) {
                int co0 = cq * 4;
                float a0 = 0.f, a1 = 0.f, a2 = 0.f, a3 = 0.f;
                for (int k = 0; k < 5; ++k) {
#pragma unroll
                    for (int ci = 0; ci < 32; ++ci) {
                        float in0 = H1[ci * 41 + pos + k];
                        const float4 wv = *(const float4*)&W2[(ci * 5 + k) * 32 + co0];
                        a0 = __builtin_fmaf(in0, wv.x, a0);
                        a1 = __builtin_fmaf(in0, wv.y, a1);
                        a2 = __builtin_fmaf(in0, wv.z, a2);
                        a3 = __builtin_fmaf(in0, wv.w, a3);
                    }
                }
                int t0 = BASE - 2 + pos;
                bool ok = (t0 >= 0 && t0 < NPTS);
                H2[(co0 + 0) * 37 + pos] = ok ? fmaxf(a0 + B2[co0 + 0], 0.0f) : 0.0f;
                H2[(co0 + 1) * 37 + pos] = ok ? fmaxf(a1 + B2[co0 + 1], 0.0f) : 0.0f;
                H2[(co0 + 2) * 37 + pos] = ok ? fmaxf(a2 + B2[co0 + 2], 0.0f) : 0.0f;
                H2[(co0 + 3) * 37 + pos] = ok ? fmaxf(a3 + B2[co0 + 3], 0.0f) : 0.0f;
            }
        }
        __syncthreads();

        if (tid < 96) {   // conv3 -> smCur rows [BASE, BASE+32); weights from LDS
            int co = tid >> 5, p = tid & 31;
            const float* w3r = W3L + co * 160;
            float acc = 0.0f;
#pragma unroll
            for (int k = 0; k < 5; ++k)
#pragma unroll
                for (int ci = 0; ci < 32; ++ci)
                    acc = __builtin_fmaf(H2[ci * 37 + p + k], w3r[ci * 5 + k], acc);
            astore(&smCur[(BASE + p) * 3 + co], acc + bb3[co]);
        }

        gsync(bar, pair - 1);   // one barrier per pair
    }

    // ---------------- merge (smoothed[p] = smfull[p] for p<7; p=7 gathered) ----------------
    {
        int pos = bid * 512 + tid;
        if (pos < TOTAL) {
            int imax = pos / STRIDE; if (imax > NCH - 1) imax = NCH - 1;
            int imin = (pos >= NPTS) ? ((pos - NPTS) / STRIDE + 1) : 0;
            float a0 = 0.0f, a1 = 0.0f, a2 = 0.0f, wsum = 0.0f;
            const float kstep = 0.9f / 1227.0f;
            const int* jmax7 = jmax_all + 6 * NPTS;
            const float* sm7 = smfull + 6 * NPTS * 3;
            for (int i = imin; i <= imax; ++i) {
                int t = pos - i * STRIDE;
                float cw;
                if (t < FADE)                cw = 0.1f + (float)t * kstep;
                else if (t >= NPTS - FADE)   cw = 1.0f - (float)(t - (NPTS - FADE)) * kstep;
                else                         cw = 1.0f;
                float vx, vy, vz;
                if (i < 7) {
                    const float* v = smfull + (i * NPTS + t) * 3;
                    vx = aload(v); vy = aload(v + 1); vz = aload(v + 2);
                } else {
                    int jm = aloadi(&jmax7[t]);
                    if (jm > 0) {
                        const float* v = sm7 + (jm - 1) * 3;
                        vx = aload(v); vy = aload(v + 1); vz = aload(v + 2);
                    } else {
                        const float* v = chunks + (7 * NPTS + t) * 3;
                        vx = v[0]; vy = v[1]; vz = v[2];
                    }
                }
                a0 += cw * vx;
                a1 += cw * vy;
                a2 += cw * vz;
                wsum += cw;
            }
            float wm = fmaxf(wsum, 1e-8f);
            out[pos * 3 + 0] = a0 / wm;
            out[pos * 3 + 1] = a1 / wm;
            out[pos * 3 + 2] = a2 / wm;
        }
    }
}

// ---------------------------------------------------------------------------
extern "C" void kernel_launch(void* const* d_in, const int* in_sizes, int n_in,
                              void* d_out, int out_size, void* d_ws, size_t ws_size,
                              hipStream_t stream) {
    const float* chunks = (const float*)d_in[0];
    const float* bs_w1 = (const float*)d_in[1];
    const float* bs_b1 = (const float*)d_in[2];
    const float* bs_w2 = (const float*)d_in[3];
    const float* bs_b2 = (const float*)d_in[4];
    const float* bs_w3 = (const float*)d_in[5];
    const float* bs_b3 = (const float*)d_in[6];
    const float* wp_w1 = (const float*)d_in[7];
    const float* wp_b1 = (const float*)d_in[8];
    const float* wp_w2 = (const float*)d_in[9];
    const float* wp_b2 = (const float*)d_in[10];
    const float* wp_w3 = (const float*)d_in[11];
    const float* wp_b3 = (const float*)d_in[12];

    unsigned* bar   = (unsigned*)d_ws;                         // 128 B (7 slots used)
    int* jmax_all   = (int*)((char*)d_ws + 128);               // 7*8192 i32
    float* smfull   = (float*)((char*)d_ws + 128 + 229376);    // 7*8192*3 f32
    float* out      = (float*)d_out;

    // zero barrier slots + jmax (j+1 encoding => 0 means "no match")
    hipMemsetAsync(d_ws, 0, 128 + 229376, stream);

    k_fusion<<<256, 512, 0, stream>>>(chunks,
        bs_w1, bs_b1, bs_w2, bs_b2, bs_w3, bs_b3,
        wp_w1, wp_b1, wp_w2, wp_b2, wp_w3, wp_b3,
        bar, jmax_all, smfull, out);
}